// Round 8
// baseline (591.281 us; speedup 1.0000x reference)
//
#include <hip/hip_runtime.h>
#include <hip/hip_bf16.h>

#define Bb 128
#define Tt 1024
#define Nn 128
#define Ss 256
#define NEGF (-1e30f)
#define D9 9.0f   // fixed log-domain shift per active step (absorbed into c at the end)

typedef __attribute__((ext_vector_type(8))) short short8;  // 8 bf16 (4 VGPRs) — MFMA A/B frag
typedef __attribute__((ext_vector_type(4))) float f32x4;   // MFMA C/D frag

__device__ __forceinline__ short bf16b(float f) {
    __hip_bfloat16 h = __float2bfloat16(f);
    return *reinterpret_cast<short*>(&h);
}

// ---- FCC per-step body.  t_ = tb + k_ (tb%8==0), k_ compile-time -> all ring
// indices fold to constants (R4 spill fix).
// R8: x-ring depth 8 (slot s holds x[tb+1+s]); ALL refills batched at k==7
// (16 loads). __syncthreads() drains vmcnt at every barrier (R7 showed any
// correct barrier does) -> with per-step loads EVERY step paid ~full HBM
// latency; batching makes 7/8 barriers drain-free and amortizes one ~900cyc
// drain per chunk.
#define FCC_STEP(t_, k_)                                                       \
    {                                                                          \
        const int t = (t_);                                                    \
        if ((k_) == 0) { /* renorm apply: wred written at k==7, post-barrier */\
            float m = fmaxf(fmaxf(wred[0][g], wred[1][g]),                     \
                            fmaxf(wred[2][g], wred[3][g]));                    \
            if (t < len) {                                                     \
                float invm = 1.0f / m;                                         \
                wc[0][0] *= invm; wc[0][1] *= invm;                            \
                wc[0][2] *= invm; wc[0][3] *= invm;                            \
                wc[1][0] *= invm; wc[1][1] *= invm;                            \
                wc[1][2] *= invm; wc[1][3] *= invm;                            \
                c += __logf(m);                                                \
            }                                                                  \
        }                                                                      \
        const short* up = &ut[(t - 1) & 1][g][0] + quad * 8;                   \
        short8 bf0 = *(const short8*)(up);                                     \
        short8 bf1 = *(const short8*)(up + 32);                                \
        short8 bf2 = *(const short8*)(up + 64);                                \
        short8 bf3 = *(const short8*)(up + 96);                                \
        f32x4 a0p = {0.f, 0.f, 0.f, 0.f}, a0q = {0.f, 0.f, 0.f, 0.f};          \
        f32x4 a1p = {0.f, 0.f, 0.f, 0.f}, a1q = {0.f, 0.f, 0.f, 0.f};          \
        a0p = __builtin_amdgcn_mfma_f32_16x16x32_bf16(ea[0][0], bf0, a0p, 0, 0, 0); \
        a1p = __builtin_amdgcn_mfma_f32_16x16x32_bf16(ea[1][0], bf0, a1p, 0, 0, 0); \
        a0q = __builtin_amdgcn_mfma_f32_16x16x32_bf16(ea[0][2], bf2, a0q, 0, 0, 0); \
        a1q = __builtin_amdgcn_mfma_f32_16x16x32_bf16(ea[1][2], bf2, a1q, 0, 0, 0); \
        a0p = __builtin_amdgcn_mfma_f32_16x16x32_bf16(ea[0][1], bf1, a0p, 0, 0, 0); \
        a1p = __builtin_amdgcn_mfma_f32_16x16x32_bf16(ea[1][1], bf1, a1p, 0, 0, 0); \
        a0q = __builtin_amdgcn_mfma_f32_16x16x32_bf16(ea[0][3], bf3, a0q, 0, 0, 0); \
        a1q = __builtin_amdgcn_mfma_f32_16x16x32_bf16(ea[1][3], bf3, a1q, 0, 0, 0); \
        const bool act = (t < len);                                            \
        float un[2][4];                                                        \
        un[0][0] = act ? wc[0][0] * (a0p[0] + a0q[0]) : uprev[0][0];           \
        un[0][1] = act ? wc[0][1] * (a0p[1] + a0q[1]) : uprev[0][1];           \
        un[0][2] = act ? wc[0][2] * (a0p[2] + a0q[2]) : uprev[0][2];           \
        un[0][3] = act ? wc[0][3] * (a0p[3] + a0q[3]) : uprev[0][3];           \
        un[1][0] = act ? wc[1][0] * (a1p[0] + a1q[0]) : uprev[1][0];           \
        un[1][1] = act ? wc[1][1] * (a1p[1] + a1q[1]) : uprev[1][1];           \
        un[1][2] = act ? wc[1][2] * (a1p[2] + a1q[2]) : uprev[1][2];           \
        un[1][3] = act ? wc[1][3] * (a1p[3] + a1q[3]) : uprev[1][3];           \
        uprev[0][0] = un[0][0]; uprev[0][1] = un[0][1];                        \
        uprev[0][2] = un[0][2]; uprev[0][3] = un[0][3];                        \
        uprev[1][0] = un[1][0]; uprev[1][1] = un[1][1];                        \
        uprev[1][2] = un[1][2]; uprev[1][3] = un[1][3];                        \
        {                                                                      \
            short4 s4;                                                         \
            s4.x = bf16b(un[0][0]); s4.y = bf16b(un[0][1]);                    \
            s4.z = bf16b(un[0][2]); s4.w = bf16b(un[0][3]);                    \
            *reinterpret_cast<short4*>(&ut[t & 1][g][j0_]) = s4;               \
            s4.x = bf16b(un[1][0]); s4.y = bf16b(un[1][1]);                    \
            s4.z = bf16b(un[1][2]); s4.w = bf16b(un[1][3]);                    \
            *reinterpret_cast<short4*>(&ut[t & 1][g][j0_ + 16]) = s4;          \
        }                                                                      \
        /* consume ring slot k_ (holds x[t+1]) into wc for step t+1 */         \
        wc[0][0] = __expf(xs[(k_)][0].x - D9);                                 \
        wc[0][1] = __expf(xs[(k_)][0].y - D9);                                 \
        wc[0][2] = __expf(xs[(k_)][0].z - D9);                                 \
        wc[0][3] = __expf(xs[(k_)][0].w - D9);                                 \
        wc[1][0] = __expf(xs[(k_)][1].x - D9);                                 \
        wc[1][1] = __expf(xs[(k_)][1].y - D9);                                 \
        wc[1][2] = __expf(xs[(k_)][1].z - D9);                                 \
        wc[1][3] = __expf(xs[(k_)][1].w - D9);                                 \
        if ((k_) == 7) {                                                       \
            /* batched refill: slots s=0..7 <- x[tb+9+s] (next chunk) */       \
            _Pragma("unroll")                                                  \
            for (int s_ = 0; s_ < 8; ++s_) {                                   \
                int kk = t + 2 + s_; if (kk > Tt - 1) kk = Tt - 1;             \
                xs[s_][0] = *(const float4*)(xb + (size_t)kk * Nn + j0_);      \
                xs[s_][1] = *(const float4*)(xb + (size_t)kk * Nn + j0_ + 16); \
            }                                                                  \
            /* renorm measure */                                               \
            float mm = un[0][0];                                               \
            mm = fmaxf(mm, un[0][1]); mm = fmaxf(mm, un[0][2]);                \
            mm = fmaxf(mm, un[0][3]); mm = fmaxf(mm, un[1][0]);                \
            mm = fmaxf(mm, un[1][1]); mm = fmaxf(mm, un[1][2]);                \
            mm = fmaxf(mm, un[1][3]);                                          \
            mm = fmaxf(mm, __shfl_xor(mm, 16));                                \
            mm = fmaxf(mm, __shfl_xor(mm, 32));                                \
            if (lane < 16) wred[q][lane] = mm;                                 \
        }                                                                      \
        __syncthreads();                                                       \
    }

// ---- FAC per-step body; d = ((k_)+7)&7 compile-time; em refilled by direct load.
#define FAC_STEP(t_, k_)                                                       \
    {                                                                          \
        const int t = (t_);                                                    \
        const int d = ((k_) + 7) & 7;                                          \
        float e0 = em[d][0], e1 = em[d][1], e2 = em[d][2], e3 = em[d][3];      \
        int tn = t + 8; if (tn > Tt - 1) tn = Tt - 1;                          \
        const float* xrow = xb + (size_t)tn * Nn;                              \
        em[d][0] = xrow[tgi[0]]; em[d][1] = xrow[tgi[1]];                      \
        em[d][2] = xrow[tgi[2]]; em[d][3] = xrow[tgi[3]];                      \
        float bup = __shfl_up(bt[3], 1);                                       \
        float prev0 = (lane == 0) ? NEGF : bup;                                \
        float nb[4];                                                           \
        {                                                                      \
            float aa = bt[0] + st[0], bb = prev0 + ntr[0];                     \
            float hi = fmaxf(aa, bb), lo = fminf(aa, bb);                      \
            nb[0] = e0 + hi + __logf(1.0f + __expf(lo - hi));                  \
        }                                                                      \
        {                                                                      \
            float aa = bt[1] + st[1], bb = bt[0] + ntr[1];                     \
            float hi = fmaxf(aa, bb), lo = fminf(aa, bb);                      \
            nb[1] = e1 + hi + __logf(1.0f + __expf(lo - hi));                  \
        }                                                                      \
        {                                                                      \
            float aa = bt[2] + st[2], bb = bt[1] + ntr[2];                     \
            float hi = fmaxf(aa, bb), lo = fminf(aa, bb);                      \
            nb[2] = e2 + hi + __logf(1.0f + __expf(lo - hi));                  \
        }                                                                      \
        {                                                                      \
            float aa = bt[3] + st[3], bb = bt[2] + ntr[3];                     \
            float hi = fmaxf(aa, bb), lo = fminf(aa, bb);                      \
            nb[3] = e3 + hi + __logf(1.0f + __expf(lo - hi));                  \
        }                                                                      \
        if (t < len) {                                                         \
            bt[0] = nb[0]; bt[1] = nb[1]; bt[2] = nb[2]; bt[3] = nb[3];        \
        }                                                                      \
    }

// blocks 0..7:  FCC, 16 batches each, MFMA 16x16x32_bf16, E in registers
// blocks 8..39: FAC, 4 batches each (1 wave per batch, wave-synchronous)
__global__ __launch_bounds__(256) void asg_main(
    const float* __restrict__ trans, const float* __restrict__ x,
    const int* __restrict__ targets, const int* __restrict__ ilen,
    const int* __restrict__ tlen,
    float* __restrict__ fcc_out, float* __restrict__ fac_out)
{
    __shared__ __align__(16) short ut[2][16][136];  // pad 8: 272 B row keeps 16B align
    __shared__ float wred[4][16];

    const int tid  = threadIdx.x;
    const int q    = tid >> 6;
    const int lane = tid & 63;
    const int g    = lane & 15;     // batch-in-group (B frag col / D frag col)
    const int quad = lane >> 4;

    if (blockIdx.x < 8) {
        // ================= FCC =================
        const int b   = (blockIdx.x << 4) + g;
        const int len = ilen[b];
        const float* xb = x + (size_t)b * Tt * Nn;

        // E A-fragments: wave q owns rows [32q, 32q+32) -> 2 M-tiles of 16.
        short8 ea[2][4];
        #pragma unroll
        for (int mt = 0; mt < 2; ++mt) {
            const float* tr = trans + (size_t)(32 * q + 16 * mt + g) * Nn + quad * 8;
            #pragma unroll
            for (int kc = 0; kc < 4; ++kc) {
                short8 v;
                #pragma unroll
                for (int jj = 0; jj < 8; ++jj)
                    v[jj] = bf16b(__expf(tr[kc * 32 + jj]));
                ea[mt][kc] = v;
            }
        }

        const int j0_ = 32 * q + 4 * quad;

        // u0 = exp(x[0]) (c = 0)
        float uprev[2][4];
        #pragma unroll
        for (int mt = 0; mt < 2; ++mt) {
            const int j0 = j0_ + 16 * mt;
            float4 xv = *(const float4*)(xb + j0);
            uprev[mt][0] = __expf(xv.x); uprev[mt][1] = __expf(xv.y);
            uprev[mt][2] = __expf(xv.z); uprev[mt][3] = __expf(xv.w);
            short4 s4;
            s4.x = bf16b(uprev[mt][0]); s4.y = bf16b(uprev[mt][1]);
            s4.z = bf16b(uprev[mt][2]); s4.w = bf16b(uprev[mt][3]);
            *reinterpret_cast<short4*>(&ut[0][g][j0]) = s4;
        }

        // wc = exp(x[1]-D9).  Ring slot s holds x[tb+1+s]; prologue acts as
        // chunk tb=0 with k=1..7, so init slots 1..7 = x[2..8] (slot 0 unused).
        float wc[2][4];
        float4 xs[8][2];
        #pragma unroll
        for (int mt = 0; mt < 2; ++mt) {
            const int j0 = j0_ + 16 * mt;
            float4 xv = *(const float4*)(xb + Nn + j0);
            wc[mt][0] = __expf(xv.x - D9); wc[mt][1] = __expf(xv.y - D9);
            wc[mt][2] = __expf(xv.z - D9); wc[mt][3] = __expf(xv.w - D9);
            #pragma unroll
            for (int s = 1; s < 8; ++s)
                xs[s][mt] = *(const float4*)(xb + (size_t)(s + 1) * Nn + j0);
        }
        float c = 0.0f;
        __syncthreads();

        // prologue t = 1..7 (k_ = t, compile-time in unrolled loop)
        #pragma unroll
        for (int k = 1; k < 8; ++k) FCC_STEP(k, k)
        // 127 chunks of 8: t = 8..1023
        for (int tb = 8; tb < Tt; tb += 8) {
            #pragma unroll
            for (int k = 0; k < 8; ++k) FCC_STEP(tb + k, k)
        }

        // every ACTIVE step multiplies u by exp(-D9); absorb into c once.
        c += D9 * (float)(len - 1);

        float s = 0.f;
        #pragma unroll
        for (int mt = 0; mt < 2; ++mt)
            #pragma unroll
            for (int r = 0; r < 4; ++r) s += uprev[mt][r];
        s += __shfl_xor(s, 16);
        s += __shfl_xor(s, 32);
        if (lane < 16) wred[q][lane] = s;
        __syncthreads();
        if (tid < 16) {
            float tot = wred[0][tid] + wred[1][tid] + wred[2][tid] + wred[3][tid];
            fcc_out[(blockIdx.x << 4) + tid] = c + __logf(tot);
        }
    } else {
        // ================= FAC (1 wave per batch, no barriers) =================
        const int b   = ((blockIdx.x - 8) << 2) + q;
        const int len = ilen[b];
        const int tl  = tlen[b];
        const float* xb = x + (size_t)b * Tt * Nn;

        int   tgi[4];
        float st[4], ntr[4], bt[4];
        #pragma unroll
        for (int r = 0; r < 4; ++r) {
            const int s = (lane << 2) + r;
            const int tgv = targets[b * Ss + s];
            const int pg  = (s == 0) ? tgv : targets[b * Ss + s - 1];
            tgi[r] = tgv;
            st[r]  = trans[tgv * Nn + tgv];
            ntr[r] = trans[tgv * Nn + pg];
            bt[r]  = (s == 0) ? xb[tgv] : NEGF;
        }
        // em ring depth 8; em[(k-1)&7] = x[k] for k=1..8 (constant indices)
        float em[8][4];
        #pragma unroll
        for (int k = 1; k <= 8; ++k) {
            int tt = k; if (tt > Tt - 1) tt = Tt - 1;
            const float* xrow = xb + (size_t)tt * Nn;
            em[(k - 1) & 7][0] = xrow[tgi[0]];
            em[(k - 1) & 7][1] = xrow[tgi[1]];
            em[(k - 1) & 7][2] = xrow[tgi[2]];
            em[(k - 1) & 7][3] = xrow[tgi[3]];
        }

        #pragma unroll
        for (int k = 1; k < 8; ++k) FAC_STEP(k, k)
        for (int tb = 8; tb < Tt; tb += 8) {
            #pragma unroll
            for (int k = 0; k < 8; ++k) FAC_STEP(tb + k, k)
        }

        #pragma unroll
        for (int r = 0; r < 4; ++r)
            if ((lane << 2) + r == tl - 1) fac_out[b] = bt[r];
    }
}

__global__ __launch_bounds__(128) void reduce_kernel(const float* __restrict__ fcc,
                                                     const float* __restrict__ fac,
                                                     float* __restrict__ out) {
    __shared__ float r2[2];
    int tid = threadIdx.x;
    float v = fcc[tid] - fac[tid];
    #pragma unroll
    for (int o = 32; o > 0; o >>= 1) v += __shfl_xor(v, o);
    if ((tid & 63) == 0) r2[tid >> 6] = v;
    __syncthreads();
    if (tid == 0) out[0] = (r2[0] + r2[1]) * (1.0f / Bb);
}

extern "C" void kernel_launch(void* const* d_in, const int* in_sizes, int n_in,
                              void* d_out, int out_size, void* d_ws, size_t ws_size,
                              hipStream_t stream) {
    const float* trans   = (const float*)d_in[0];
    const float* x       = (const float*)d_in[1];
    const int*   targets = (const int*)d_in[2];
    const int*   ilen    = (const int*)d_in[3];
    const int*   tlen    = (const int*)d_in[4];
    float* out = (float*)d_out;

    float* fcc = (float*)d_ws;       // B floats
    float* fac = fcc + Bb;           // B floats

    asg_main<<<8 + Bb / 4, 256, 0, stream>>>(trans, x, targets, ilen, tlen, fcc, fac);
    reduce_kernel<<<1, 128, 0, stream>>>(fcc, fac, out);
}